// Round 1
// baseline (317.146 us; speedup 1.0000x reference)
//
#include <hip/hip_runtime.h>

#define ZD 21
#define YD 256
#define XD 256
#define BD 2
#define NCIN 16
#define NC1 32
#define NC2 64
#define BN_EPS 1e-3f

typedef __attribute__((ext_vector_type(8))) short short8;
typedef __attribute__((ext_vector_type(4))) float floatx4;

__device__ inline unsigned short rne_bf16(float w) {
    unsigned b = __float_as_uint(w);
    return (unsigned short)((b + 0x7FFFu + ((b >> 16) & 1u)) >> 16);
}

__global__ __launch_bounds__(256) void scatter_grid_k(const int* __restrict__ coors,
                                                      int* __restrict__ grid, int n) {
    int i = blockIdx.x * 256 + threadIdx.x;
    if (i >= n) return;
    const int4 c = ((const int4*)coors)[i];   // [b, z, y, x]
    const int lin = ((c.x * ZD + c.y) * YD + c.z) * XD + c.w;
    grid[lin] = i;
}

// Pack W1 (pairs of offsets stacked to K=32) and W2 into MFMA B-fragment
// layout, single bf16 (RNE). B-frag 16x16x32: lane holds B[k=(lane>>4)*8+j][n=lane&15].
__global__ __launch_bounds__(256) void pack_w_k(const float* __restrict__ W1,
                                                const float* __restrict__ W2,
                                                short* __restrict__ wp1,
                                                short* __restrict__ wp2) {
    int t = blockIdx.x * 256 + threadIdx.x;
    if (t < 14 * 2 * 512) {               // Wp1: [pair][cb][512]
        int pair = t / 1024, r = t % 1024, cb = r / 512, e = r % 512;
        int lane = e / 8, j = e % 8, kk = (lane >> 4) * 8 + j;
        int ko = pair * 2 + (kk >> 4), ci = kk & 15, co = cb * 16 + (lane & 15);
        float w = (ko < 27) ? W1[(ko * NCIN + ci) * NC1 + co] : 0.f;
        wp1[(pair * 2 + cb) * 512 + e] = (short)rne_bf16(w);
    }
    int t2 = t - 14 * 2 * 512;
    if (t2 >= 0 && t2 < 27 * 4 * 512) {   // Wp2: [k][cb][512]
        int k = t2 / 2048, r = t2 % 2048, cb = r / 512, e = r % 512;
        int lane = e / 8, j = e % 8, ci = (lane >> 4) * 8 + j, co = cb * 16 + (lane & 15);
        wp2[(k * 4 + cb) * 512 + e] = (short)rne_bf16(W2[(k * NC1 + ci) * NC2 + co]);
    }
}

// wave = 64 output voxels (4 M-tiles of 16). K=32 = two 3x3x3 offsets x 16 ci.
// FULL coverage: wave stride 64, block stride 256, grid = ceil(n/256).
// 1-deep prefetch of next pair's grid lookups hides gather latency under MFMA.
__global__ __launch_bounds__(256, 4) void conv1_k(
    const float* __restrict__ feat, const int* __restrict__ coors,
    const short* __restrict__ wp1,
    const float* __restrict__ g1, const float* __restrict__ b1,
    const float* __restrict__ m1, const float* __restrict__ v1,
    const int* __restrict__ grid, unsigned short* __restrict__ f1, int n) {
    const int tid = threadIdx.x;
    const int lane = tid & 63;
    const int quad = lane >> 4;
    const int mrow = lane & 15;
    const int vbase = blockIdx.x * 256 + (tid >> 6) * 64;

    int bb[4], z0[4], y0[4], x0[4];
    bool rok[4];
#pragma unroll
    for (int mt = 0; mt < 4; ++mt) {
        const int v = vbase + mt * 16 + mrow;
        rok[mt] = v < n;
        bb[mt] = 0; z0[mt] = 0; y0[mt] = 0; x0[mt] = 0;
        if (rok[mt]) {
            const int4 cc = ((const int4*)coors)[v];
            bb[mt] = cc.x; z0[mt] = cc.y; y0[mt] = cc.z; x0[mt] = cc.w;
        }
    }

    floatx4 d[4][2];
#pragma unroll
    for (int mt = 0; mt < 4; ++mt)
#pragma unroll
        for (int cb = 0; cb < 2; ++cb) d[mt][cb] = (floatx4){0.f, 0.f, 0.f, 0.f};

    const short8* __restrict__ wb = (const short8*)wp1;
    const int ko_add = quad >> 1;     // this quad's offset within the pair
    const int ci_half = quad & 1;     // this quad's input-channel half

    // prologue: lookups for pair 0
    int idxc[4];
#pragma unroll
    for (int mt = 0; mt < 4; ++mt) {
        int idx = -1;
        const int ko = ko_add;
        if (rok[mt]) {
            const int z = z0[mt] + ko / 9 - 1;
            const int y = y0[mt] + (ko / 3) % 3 - 1;
            const int x = x0[mt] + ko % 3 - 1;
            if ((unsigned)z < ZD && (unsigned)y < YD && (unsigned)x < XD)
                idx = grid[((bb[mt] * ZD + z) * YD + y) * XD + x];
        }
        idxc[mt] = idx;
    }

#pragma unroll 1
    for (int pair = 0; pair < 14; ++pair) {
        short8 a[4];
        unsigned long long bm[4];
#pragma unroll
        for (int mt = 0; mt < 4; ++mt) {
            bm[mt] = __ballot(idxc[mt] >= 0);
            a[mt] = (short8)0;
            if (idxc[mt] >= 0) {
                const float4* fr = (const float4*)(feat + (size_t)idxc[mt] * NCIN + ci_half * 8);
                const float4 p = fr[0], q = fr[1];
                const float v8[8] = {p.x, p.y, p.z, p.w, q.x, q.y, q.z, q.w};
#pragma unroll
                for (int i = 0; i < 8; ++i) a[mt][i] = (short)rne_bf16(v8[i]);
            }
        }
        // prefetch next pair's neighbor indices
        if (pair < 13) {
            const int ko = (pair + 1) * 2 + ko_add;
#pragma unroll
            for (int mt = 0; mt < 4; ++mt) {
                int idx = -1;
                if (rok[mt] && ko < 27) {
                    const int z = z0[mt] + ko / 9 - 1;
                    const int y = y0[mt] + (ko / 3) % 3 - 1;
                    const int x = x0[mt] + ko % 3 - 1;
                    if ((unsigned)z < ZD && (unsigned)y < YD && (unsigned)x < XD)
                        idx = grid[((bb[mt] * ZD + z) * YD + y) * XD + x];
                }
                idxc[mt] = idx;
            }
        }
        const short8 bw0 = wb[(pair * 2 + 0) * 64 + lane];
        const short8 bw1 = wb[(pair * 2 + 1) * 64 + lane];
#pragma unroll
        for (int mt = 0; mt < 4; ++mt) {
            if (bm[mt]) {
                d[mt][0] = __builtin_amdgcn_mfma_f32_16x16x32_bf16(a[mt], bw0, d[mt][0], 0, 0, 0);
                d[mt][1] = __builtin_amdgcn_mfma_f32_16x16x32_bf16(a[mt], bw1, d[mt][1], 0, 0, 0);
            }
        }
    }

    // C/D layout: col = lane&15 (channel), row = quad*4 + reg (voxel)
    const int col = lane & 15;
#pragma unroll
    for (int cb = 0; cb < 2; ++cb) {
        const int ch = cb * 16 + col;
        const float sc = g1[ch] * rsqrtf(v1[ch] + BN_EPS);
        const float sb = b1[ch] - m1[ch] * sc;
#pragma unroll
        for (int mt = 0; mt < 4; ++mt) {
#pragma unroll
            for (int r = 0; r < 4; ++r) {
                const int v = vbase + mt * 16 + quad * 4 + r;
                if (v < n) {
                    const float o = fmaxf(fmaf(d[mt][cb][r], sc, sb), 0.f);
                    f1[(size_t)v * NC1 + ch] = rne_bf16(o);
                }
            }
        }
    }
}

// wave = 64 output voxels (4 M-tiles), N=64 (4 col-blocks), K=32 = ci per offset.
// FULL coverage, bf16 single-term, prefetched rulebook lookups.
__global__ __launch_bounds__(256, 3) void conv2_k(
    const unsigned short* __restrict__ f1,
    const int* __restrict__ ocoors, const short* __restrict__ wp2,
    const float* __restrict__ g2, const float* __restrict__ b2,
    const float* __restrict__ m2, const float* __restrict__ v2,
    const int* __restrict__ grid, float* __restrict__ out, int m) {
    const int tid = threadIdx.x;
    const int lane = tid & 63;
    const int quad = lane >> 4;
    const int mrow = lane & 15;
    const int vbase = blockIdx.x * 256 + (tid >> 6) * 64;

    int bb[4], z0[4], y0[4], x0[4];
    bool rok[4];
#pragma unroll
    for (int mt = 0; mt < 4; ++mt) {
        const int v = vbase + mt * 16 + mrow;
        rok[mt] = v < m;
        bb[mt] = 0; z0[mt] = 0; y0[mt] = 0; x0[mt] = 0;
        if (rok[mt]) {
            const int4 cc = ((const int4*)ocoors)[v];
            bb[mt] = cc.x; z0[mt] = cc.y * 2; y0[mt] = cc.z * 2 - 1; x0[mt] = cc.w * 2 - 1;
        }
    }

    floatx4 d[4][4];
#pragma unroll
    for (int mt = 0; mt < 4; ++mt)
#pragma unroll
        for (int cb = 0; cb < 4; ++cb) d[mt][cb] = (floatx4){0.f, 0.f, 0.f, 0.f};

    const short8* __restrict__ wb = (const short8*)wp2;

    // prologue: lookups for k=0 (dz=dy=dx=0)
    int idxc[4];
#pragma unroll
    for (int mt = 0; mt < 4; ++mt) {
        int idx = -1;
        const int z = z0[mt], y = y0[mt], x = x0[mt];
        if (rok[mt] && (unsigned)z < ZD && (unsigned)y < YD && (unsigned)x < XD)
            idx = grid[((bb[mt] * ZD + z) * YD + y) * XD + x];
        idxc[mt] = idx;
    }

#pragma unroll 1
    for (int k = 0; k < 27; ++k) {
        short8 a[4];
        unsigned long long bm[4];
#pragma unroll
        for (int mt = 0; mt < 4; ++mt) {
            bm[mt] = __ballot(idxc[mt] >= 0);
            a[mt] = (short8)0;
            if (idxc[mt] >= 0)
                a[mt] = *(const short8*)(f1 + (size_t)idxc[mt] * NC1 + quad * 8);
        }
        // prefetch next k's neighbor indices
        if (k < 26) {
            const int kn = k + 1;
            const int dz = kn / 9, dy = (kn / 3) % 3, dx = kn % 3;
#pragma unroll
            for (int mt = 0; mt < 4; ++mt) {
                int idx = -1;
                const int z = z0[mt] + dz, y = y0[mt] + dy, x = x0[mt] + dx;
                if (rok[mt] && (unsigned)z < ZD && (unsigned)y < YD && (unsigned)x < XD)
                    idx = grid[((bb[mt] * ZD + z) * YD + y) * XD + x];
                idxc[mt] = idx;
            }
        }
#pragma unroll
        for (int cb = 0; cb < 4; ++cb) {
            const short8 bh = wb[(k * 4 + cb) * 64 + lane];
#pragma unroll
            for (int mt = 0; mt < 4; ++mt) {
                if (bm[mt])
                    d[mt][cb] = __builtin_amdgcn_mfma_f32_16x16x32_bf16(a[mt], bh, d[mt][cb], 0, 0, 0);
            }
        }
    }

    const int col = lane & 15;
#pragma unroll
    for (int cb = 0; cb < 4; ++cb) {
        const int ch = cb * 16 + col;
        const float sc = g2[ch] * rsqrtf(v2[ch] + BN_EPS);
        const float sb = b2[ch] - m2[ch] * sc;
#pragma unroll
        for (int mt = 0; mt < 4; ++mt) {
#pragma unroll
            for (int r = 0; r < 4; ++r) {
                const int v = vbase + mt * 16 + quad * 4 + r;
                if (v < m)
                    out[(size_t)v * NC2 + ch] = fmaxf(fmaf(d[mt][cb][r], sc, sb), 0.f);
            }
        }
    }
}

// out_coors passthrough (as float values) + batch_size
__global__ __launch_bounds__(256) void tail_k(const int* __restrict__ oc,
                                              const int* __restrict__ bs,
                                              float* __restrict__ out, int m4) {
    int i = blockIdx.x * 256 + threadIdx.x;
    if (i < m4) out[i] = (float)oc[i];
    if (i == m4) out[m4] = (float)bs[0];
}

extern "C" void kernel_launch(void* const* d_in, const int* in_sizes, int n_in,
                              void* d_out, int out_size, void* d_ws, size_t ws_size,
                              hipStream_t stream) {
    const float* feat  = (const float*)d_in[0];
    const int*   coors = (const int*)d_in[1];
    const int*   ocoors= (const int*)d_in[2];
    const float* W1 = (const float*)d_in[3];
    const float* g1 = (const float*)d_in[4];
    const float* b1 = (const float*)d_in[5];
    const float* m1 = (const float*)d_in[6];
    const float* v1 = (const float*)d_in[7];
    const float* W2 = (const float*)d_in[8];
    const float* g2 = (const float*)d_in[9];
    const float* b2 = (const float*)d_in[10];
    const float* m2 = (const float*)d_in[11];
    const float* v2 = (const float*)d_in[12];
    const int*   bs = (const int*)d_in[13];

    const int n = in_sizes[0] / NCIN;
    const int m = in_sizes[2] / 4;

    const size_t GRID_N = (size_t)BD * ZD * YD * XD;
    char* ws = (char*)d_ws;
    int* grid = (int*)ws;
    size_t off = (GRID_N * sizeof(int) + 255) & ~(size_t)255;
    unsigned short* f1 = (unsigned short*)(ws + off);
    off += ((size_t)n * NC1 * 2 + 255) & ~(size_t)255;
    short* wp1 = (short*)(ws + off);
    off += (14 * 2 * 512 * 2 + 255) & ~(size_t)255;
    short* wp2 = (short*)(ws + off);

    hipMemsetAsync(grid, 0xFF, GRID_N * sizeof(int), stream);
    scatter_grid_k<<<(n + 255) / 256, 256, 0, stream>>>(coors, grid, n);
    pack_w_k<<<(14 * 2 * 512 + 27 * 4 * 512 + 255) / 256, 256, 0, stream>>>(W1, W2, wp1, wp2);

    conv1_k<<<(n + 255) / 256, 256, 0, stream>>>(feat, coors, wp1, g1, b1, m1, v1,
                                                 grid, f1, n);

    float* out = (float*)d_out;
    conv2_k<<<(m + 255) / 256, 256, 0, stream>>>(f1, ocoors, wp2,
                                                 g2, b2, m2, v2, grid, out, m);
    tail_k<<<(m * 4 + 1 + 255) / 256, 256, 0, stream>>>(ocoors, bs, out + (size_t)m * NC2, m * 4);
}

// Round 2
// 259.809 us; speedup vs baseline: 1.2207x; 1.2207x over previous
//
#include <hip/hip_runtime.h>

#define ZD 21
#define YD 256
#define XD 256
#define BD 2
#define NCIN 16
#define NC1 32
#define NC2 64
#define BN_EPS 1e-3f

// halo-padded rulebook grid: z,y,x each padded by 1 on both sides
#define ZP 23
#define YP 258
#define XP 258
#define YPXP 66564               // YP*XP
#define GRID_TOT (BD * ZP * YPXP)  // 3,061,944
#define TAILN 133647             // max KOFF + 1; always-(-1) region for invalid rows

typedef __attribute__((ext_vector_type(8))) short short8;
typedef __attribute__((ext_vector_type(4))) float floatx4;

// KOFF[k] = dz*YPXP + dy*XP + dx for (dz,dy,dx) in {0,1,2}^3 lexicographic; [27] = 0 pad
__constant__ int KOFF[28] = {
    0, 1, 2, 258, 259, 260, 516, 517, 518,
    66564, 66565, 66566, 66822, 66823, 66824, 67080, 67081, 67082,
    133128, 133129, 133130, 133386, 133387, 133388, 133644, 133645, 133646,
    0};

__device__ inline unsigned short rne_bf16(float w) {
    unsigned b = __float_as_uint(w);
    return (unsigned short)((b + 0x7FFFu + ((b >> 16) & 1u)) >> 16);
}

__global__ __launch_bounds__(256) void scatter_grid_k(const int* __restrict__ coors,
                                                      int* __restrict__ grid, int n) {
    int i = blockIdx.x * 256 + threadIdx.x;
    if (i >= n) return;
    const int4 c = ((const int4*)coors)[i];   // [b, z, y, x]
    const int lin = ((c.x * ZP + c.y + 1) * YP + c.z + 1) * XP + c.w + 1;
    grid[lin] = i;
}

// feat (f32, n x 16) -> bf16 once; conv1 then gathers 16B rows directly
__global__ __launch_bounds__(256) void feat2bf_k(const float* __restrict__ feat,
                                                 unsigned short* __restrict__ fb, int n8) {
    int i = blockIdx.x * 256 + threadIdx.x;
    if (i >= n8) return;
    const float4* p = (const float4*)feat + (size_t)i * 2;
    const float4 a = p[0], b = p[1];
    short8 o;
    o[0] = (short)rne_bf16(a.x); o[1] = (short)rne_bf16(a.y);
    o[2] = (short)rne_bf16(a.z); o[3] = (short)rne_bf16(a.w);
    o[4] = (short)rne_bf16(b.x); o[5] = (short)rne_bf16(b.y);
    o[6] = (short)rne_bf16(b.z); o[7] = (short)rne_bf16(b.w);
    ((short8*)fb)[i] = o;
}

// Pack W1 (pairs of offsets stacked to K=32) and W2 into MFMA B-fragment
// layout, single bf16 (RNE). B-frag 16x16x32: lane holds B[k=(lane>>4)*8+j][n=lane&15].
__global__ __launch_bounds__(256) void pack_w_k(const float* __restrict__ W1,
                                                const float* __restrict__ W2,
                                                short* __restrict__ wp1,
                                                short* __restrict__ wp2) {
    int t = blockIdx.x * 256 + threadIdx.x;
    if (t < 14 * 2 * 512) {               // Wp1: [pair][cb][512]
        int pair = t / 1024, r = t % 1024, cb = r / 512, e = r % 512;
        int lane = e / 8, j = e % 8, kk = (lane >> 4) * 8 + j;
        int ko = pair * 2 + (kk >> 4), ci = kk & 15, co = cb * 16 + (lane & 15);
        float w = (ko < 27) ? W1[(ko * NCIN + ci) * NC1 + co] : 0.f;
        wp1[(pair * 2 + cb) * 512 + e] = (short)rne_bf16(w);
    }
    int t2 = t - 14 * 2 * 512;
    if (t2 >= 0 && t2 < 27 * 4 * 512) {   // Wp2: [k][cb][512]
        int k = t2 / 2048, r = t2 % 2048, cb = r / 512, e = r % 512;
        int lane = e / 8, j = e % 8, ci = (lane >> 4) * 8 + j, co = cb * 16 + (lane & 15);
        wp2[(k * 4 + cb) * 512 + e] = (short)rne_bf16(W2[(k * NC1 + ci) * NC2 + co]);
    }
}

// wave = 64 output voxels (4 M-tiles of 16). K=32 = two 3x3x3 offsets x 16 ci.
// Padded grid: per-tap address = pb + KOFF (no bounds checks, no div/mod).
// 2-deep pipeline: idx(p+2) prefetch, A(p+1) gather, MFMA on A(p).
__global__ __launch_bounds__(256, 4) void conv1_k(
    const unsigned short* __restrict__ featb, const int* __restrict__ coors,
    const short* __restrict__ wp1,
    const float* __restrict__ g1, const float* __restrict__ b1,
    const float* __restrict__ m1, const float* __restrict__ v1,
    const int* __restrict__ gridp, unsigned short* __restrict__ f1, int n, int tail0) {
    const int tid = threadIdx.x;
    const int lane = tid & 63;
    const int quad = lane >> 4;
    const int mrow = lane & 15;
    const int vbase = blockIdx.x * 256 + (tid >> 6) * 64;
    const int ko_add = quad >> 1;     // this quad's offset within the pair
    const int ci_half = quad & 1;     // this quad's input-channel half

    int pb[4];
#pragma unroll
    for (int mt = 0; mt < 4; ++mt) {
        const int v = vbase + mt * 16 + mrow;
        if (v < n) {
            const int4 cc = ((const int4*)coors)[v];
            pb[mt] = ((cc.x * ZP + cc.y) * YP + cc.z) * XP + cc.w;
        } else {
            pb[mt] = tail0;   // always-(-1) tail region
        }
    }

    floatx4 d[4][2];
#pragma unroll
    for (int mt = 0; mt < 4; ++mt)
#pragma unroll
        for (int cb = 0; cb < 2; ++cb) d[mt][cb] = (floatx4){0.f, 0.f, 0.f, 0.f};

    const short8* __restrict__ wb = (const short8*)wp1;

    // prologue: idx for pair 0 and pair 1, A for pair 0, W for pair 0
    int id_c[4], id_n[4];
    {
        const int koff = ko_add ? KOFF[1] : KOFF[0];
#pragma unroll
        for (int mt = 0; mt < 4; ++mt) id_c[mt] = gridp[pb[mt] + koff];
    }
    {
        const int koff = ko_add ? KOFF[3] : KOFF[2];
#pragma unroll
        for (int mt = 0; mt < 4; ++mt) id_n[mt] = gridp[pb[mt] + koff];
    }
    short8 a_c[4];
#pragma unroll
    for (int mt = 0; mt < 4; ++mt) {
        a_c[mt] = (short8)0;
        if (id_c[mt] >= 0)
            a_c[mt] = *(const short8*)(featb + (unsigned)(id_c[mt] * NCIN + ci_half * 8));
    }
    short8 w0_c = wb[0 * 64 + lane];
    short8 w1_c = wb[1 * 64 + lane];

#pragma unroll 2
    for (int pair = 0; pair < 14; ++pair) {
        unsigned long long bm[4];
#pragma unroll
        for (int mt = 0; mt < 4; ++mt) bm[mt] = __ballot(id_c[mt] >= 0);

        // gather A for pair+1 (id_n is -1-safe; extra gathers past the end are harmless)
        short8 a_nx[4];
#pragma unroll
        for (int mt = 0; mt < 4; ++mt) {
            a_nx[mt] = (short8)0;
            if (id_n[mt] >= 0)
                a_nx[mt] = *(const short8*)(featb + (unsigned)(id_n[mt] * NCIN + ci_half * 8));
        }
        // prefetch idx for pair+2 (clamped; results past the end are rotated away)
        int id_f[4];
        {
            const int kbase = (pair < 12) ? (pair + 2) * 2 : 26;
            const int koff = ko_add ? KOFF[kbase + 1] : KOFF[kbase];
#pragma unroll
            for (int mt = 0; mt < 4; ++mt) id_f[mt] = gridp[pb[mt] + koff];
        }
        // prefetch weights for pair+1
        const int kn = (pair < 13) ? pair + 1 : 13;
        const short8 w0_n = wb[(kn * 2 + 0) * 64 + lane];
        const short8 w1_n = wb[(kn * 2 + 1) * 64 + lane];

#pragma unroll
        for (int mt = 0; mt < 4; ++mt) {
            if (bm[mt]) {
                d[mt][0] = __builtin_amdgcn_mfma_f32_16x16x32_bf16(a_c[mt], w0_c, d[mt][0], 0, 0, 0);
                d[mt][1] = __builtin_amdgcn_mfma_f32_16x16x32_bf16(a_c[mt], w1_c, d[mt][1], 0, 0, 0);
            }
        }
#pragma unroll
        for (int mt = 0; mt < 4; ++mt) {
            a_c[mt] = a_nx[mt]; id_c[mt] = id_n[mt]; id_n[mt] = id_f[mt];
        }
        w0_c = w0_n; w1_c = w1_n;
    }

    // C/D layout: col = lane&15 (channel), row = quad*4 + reg (voxel)
    const int col = lane & 15;
#pragma unroll
    for (int cb = 0; cb < 2; ++cb) {
        const int ch = cb * 16 + col;
        const float sc = g1[ch] * rsqrtf(v1[ch] + BN_EPS);
        const float sb = b1[ch] - m1[ch] * sc;
#pragma unroll
        for (int mt = 0; mt < 4; ++mt) {
#pragma unroll
            for (int r = 0; r < 4; ++r) {
                const int v = vbase + mt * 16 + quad * 4 + r;
                if (v < n) {
                    const float o = fmaxf(fmaf(d[mt][cb][r], sc, sb), 0.f);
                    f1[(unsigned)(v * NC1 + ch)] = rne_bf16(o);
                }
            }
        }
    }
}

// wave = 64 output voxels (4 M-tiles), N=64 (4 col-blocks), K=32 = ci per offset.
// Padded grid + 2-deep pipeline, same structure as conv1.
__global__ __launch_bounds__(256, 3) void conv2_k(
    const unsigned short* __restrict__ f1,
    const int* __restrict__ ocoors, const short* __restrict__ wp2,
    const float* __restrict__ g2, const float* __restrict__ b2,
    const float* __restrict__ m2, const float* __restrict__ v2,
    const int* __restrict__ gridp, float* __restrict__ out, int m, int tail0) {
    const int tid = threadIdx.x;
    const int lane = tid & 63;
    const int quad = lane >> 4;
    const int mrow = lane & 15;
    const int vbase = blockIdx.x * 256 + (tid >> 6) * 64;

    int pb[4];
#pragma unroll
    for (int mt = 0; mt < 4; ++mt) {
        const int v = vbase + mt * 16 + mrow;
        if (v < m) {
            const int4 cc = ((const int4*)ocoors)[v];
            // real z = 2*cc.y + dz  -> padded base z-part = 2*cc.y + 1
            // real y = 2*cc.z - 1 + dy -> padded base y-part = 2*cc.z; same for x
            pb[mt] = ((cc.x * ZP + 2 * cc.y + 1) * YP + 2 * cc.z) * XP + 2 * cc.w;
        } else {
            pb[mt] = tail0;
        }
    }

    floatx4 d[4][4];
#pragma unroll
    for (int mt = 0; mt < 4; ++mt)
#pragma unroll
        for (int cb = 0; cb < 4; ++cb) d[mt][cb] = (floatx4){0.f, 0.f, 0.f, 0.f};

    const short8* __restrict__ wb = (const short8*)wp2;

    // prologue
    int id_c[4], id_n[4];
#pragma unroll
    for (int mt = 0; mt < 4; ++mt) id_c[mt] = gridp[pb[mt] + KOFF[0]];
#pragma unroll
    for (int mt = 0; mt < 4; ++mt) id_n[mt] = gridp[pb[mt] + KOFF[1]];
    short8 a_c[4];
#pragma unroll
    for (int mt = 0; mt < 4; ++mt) {
        a_c[mt] = (short8)0;
        if (id_c[mt] >= 0)
            a_c[mt] = *(const short8*)(f1 + (unsigned)(id_c[mt] * NC1 + quad * 8));
    }
    short8 w_c[4];
#pragma unroll
    for (int cb = 0; cb < 4; ++cb) w_c[cb] = wb[(0 * 4 + cb) * 64 + lane];

#pragma unroll 2
    for (int k = 0; k < 27; ++k) {
        unsigned long long bm[4];
#pragma unroll
        for (int mt = 0; mt < 4; ++mt) bm[mt] = __ballot(id_c[mt] >= 0);

        short8 a_nx[4];
#pragma unroll
        for (int mt = 0; mt < 4; ++mt) {
            a_nx[mt] = (short8)0;
            if (id_n[mt] >= 0)
                a_nx[mt] = *(const short8*)(f1 + (unsigned)(id_n[mt] * NC1 + quad * 8));
        }
        int id_f[4];
        {
            const int koff = KOFF[(k < 25) ? k + 2 : 26];
#pragma unroll
            for (int mt = 0; mt < 4; ++mt) id_f[mt] = gridp[pb[mt] + koff];
        }
        const int kn = (k < 26) ? k + 1 : 26;
        short8 w_n[4];
#pragma unroll
        for (int cb = 0; cb < 4; ++cb) w_n[cb] = wb[(kn * 4 + cb) * 64 + lane];

#pragma unroll
        for (int mt = 0; mt < 4; ++mt) {
            if (bm[mt]) {
#pragma unroll
                for (int cb = 0; cb < 4; ++cb)
                    d[mt][cb] = __builtin_amdgcn_mfma_f32_16x16x32_bf16(a_c[mt], w_c[cb], d[mt][cb], 0, 0, 0);
            }
        }
#pragma unroll
        for (int mt = 0; mt < 4; ++mt) {
            a_c[mt] = a_nx[mt]; id_c[mt] = id_n[mt]; id_n[mt] = id_f[mt];
        }
#pragma unroll
        for (int cb = 0; cb < 4; ++cb) w_c[cb] = w_n[cb];
    }

    const int col = lane & 15;
#pragma unroll
    for (int cb = 0; cb < 4; ++cb) {
        const int ch = cb * 16 + col;
        const float sc = g2[ch] * rsqrtf(v2[ch] + BN_EPS);
        const float sb = b2[ch] - m2[ch] * sc;
#pragma unroll
        for (int mt = 0; mt < 4; ++mt) {
#pragma unroll
            for (int r = 0; r < 4; ++r) {
                const int v = vbase + mt * 16 + quad * 4 + r;
                if (v < m)
                    out[(unsigned)(v * NC2 + ch)] = fmaxf(fmaf(d[mt][cb][r], sc, sb), 0.f);
            }
        }
    }
}

// out_coors passthrough (as float values) + batch_size
__global__ __launch_bounds__(256) void tail_k(const int* __restrict__ oc,
                                              const int* __restrict__ bs,
                                              float* __restrict__ out, int m4) {
    int i = blockIdx.x * 256 + threadIdx.x;
    if (i < m4) out[i] = (float)oc[i];
    if (i == m4) out[m4] = (float)bs[0];
}

extern "C" void kernel_launch(void* const* d_in, const int* in_sizes, int n_in,
                              void* d_out, int out_size, void* d_ws, size_t ws_size,
                              hipStream_t stream) {
    const float* feat  = (const float*)d_in[0];
    const int*   coors = (const int*)d_in[1];
    const int*   ocoors= (const int*)d_in[2];
    const float* W1 = (const float*)d_in[3];
    const float* g1 = (const float*)d_in[4];
    const float* b1 = (const float*)d_in[5];
    const float* m1 = (const float*)d_in[6];
    const float* v1 = (const float*)d_in[7];
    const float* W2 = (const float*)d_in[8];
    const float* g2 = (const float*)d_in[9];
    const float* b2 = (const float*)d_in[10];
    const float* m2 = (const float*)d_in[11];
    const float* v2 = (const float*)d_in[12];
    const int*   bs = (const int*)d_in[13];

    const int n = in_sizes[0] / NCIN;
    const int m = in_sizes[2] / 4;

    char* ws = (char*)d_ws;
    int* grid = (int*)ws;
    size_t off = ((size_t)(GRID_TOT + TAILN) * sizeof(int) + 255) & ~(size_t)255;
    unsigned short* featb = (unsigned short*)(ws + off);
    off += ((size_t)n * NCIN * 2 + 255) & ~(size_t)255;
    unsigned short* f1 = (unsigned short*)(ws + off);
    off += ((size_t)n * NC1 * 2 + 255) & ~(size_t)255;
    short* wp1 = (short*)(ws + off);
    off += (14 * 2 * 512 * 2 + 255) & ~(size_t)255;
    short* wp2 = (short*)(ws + off);

    hipMemsetAsync(grid, 0xFF, (size_t)(GRID_TOT + TAILN) * sizeof(int), stream);
    scatter_grid_k<<<(n + 255) / 256, 256, 0, stream>>>(coors, grid, n);
    feat2bf_k<<<(n * 2 + 255) / 256, 256, 0, stream>>>(feat, featb, n * 2);
    pack_w_k<<<(14 * 2 * 512 + 27 * 4 * 512 + 255) / 256, 256, 0, stream>>>(W1, W2, wp1, wp2);

    conv1_k<<<(n + 255) / 256, 256, 0, stream>>>(featb, coors, wp1, g1, b1, m1, v1,
                                                 grid, f1, n, GRID_TOT);

    float* out = (float*)d_out;
    conv2_k<<<(m + 255) / 256, 256, 0, stream>>>(f1, ocoors, wp2,
                                                 g2, b2, m2, v2, grid, out, m, GRID_TOT);
    tail_k<<<(m * 4 + 1 + 255) / 256, 256, 0, stream>>>(ocoors, bs, out + (size_t)m * NC2, m * 4);
}

// Round 4
// 237.475 us; speedup vs baseline: 1.3355x; 1.0940x over previous
//
#include <hip/hip_runtime.h>

#define ZD 21
#define YD 256
#define XD 256
#define BD 2
#define NCIN 16
#define NC1 32
#define NC2 64
#define BN_EPS 1e-3f

// halo-padded rulebook grid: z,y,x each padded by 1 on both sides
#define ZP 23
#define YP 258
#define XP 258
#define YPXP 66564               // YP*XP
#define GRID_TOT (BD * ZP * YPXP)  // 3,061,944
#define TAILN 133647             // max KOFF + 1; always-(-1) region for invalid rows

typedef __attribute__((ext_vector_type(8))) short short8;
typedef __attribute__((ext_vector_type(4))) float floatx4;

// KOFF[k] = dz*YPXP + dy*XP + dx for (dz,dy,dx) in {0,1,2}^3 lexicographic; [27] = 0 pad
__constant__ int KOFF[28] = {
    0, 1, 2, 258, 259, 260, 516, 517, 518,
    66564, 66565, 66566, 66822, 66823, 66824, 67080, 67081, 67082,
    133128, 133129, 133130, 133386, 133387, 133388, 133644, 133645, 133646,
    0};

__device__ inline unsigned short rne_bf16(float w) {
    unsigned b = __float_as_uint(w);
    return (unsigned short)((b + 0x7FFFu + ((b >> 16) & 1u)) >> 16);
}

// Fused prep: grid scatter + feat->bf16 + weight packing + out_coors tail.
// Grid must cover max(2n, m4+1) threads (m4 = 4*m > 2n here!).
__global__ __launch_bounds__(256) void prep_k(
    const float* __restrict__ feat, const int* __restrict__ coors,
    const float* __restrict__ W1, const float* __restrict__ W2,
    const int* __restrict__ oc, const int* __restrict__ bs,
    int* __restrict__ grid, unsigned short* __restrict__ featb,
    short* __restrict__ wp1, short* __restrict__ wp2,
    float* __restrict__ out2, int n, int m4) {
    const int i = blockIdx.x * 256 + threadIdx.x;

    if (i < n) {                          // scatter voxel id into padded grid
        const int4 c = ((const int4*)coors)[i];   // [b, z, y, x]
        grid[((c.x * ZP + c.y + 1) * YP + c.z + 1) * XP + c.w + 1] = i;
    }
    if (i < 2 * n) {                      // feat f32 -> bf16 (8 ch per thread)
        const float4* p = (const float4*)feat + (size_t)i * 2;
        const float4 a = p[0], b = p[1];
        short8 o;
        o[0] = (short)rne_bf16(a.x); o[1] = (short)rne_bf16(a.y);
        o[2] = (short)rne_bf16(a.z); o[3] = (short)rne_bf16(a.w);
        o[4] = (short)rne_bf16(b.x); o[5] = (short)rne_bf16(b.y);
        o[6] = (short)rne_bf16(b.z); o[7] = (short)rne_bf16(b.w);
        ((short8*)featb)[i] = o;
    }
    if (i < 14 * 2 * 512) {               // Wp1: [pair][cb][512]
        int pair = i / 1024, r = i % 1024, cb = r / 512, e = r % 512;
        int lane = e / 8, j = e % 8, kk = (lane >> 4) * 8 + j;
        int ko = pair * 2 + (kk >> 4), ci = kk & 15, co = cb * 16 + (lane & 15);
        float w = (ko < 27) ? W1[(ko * NCIN + ci) * NC1 + co] : 0.f;
        wp1[(pair * 2 + cb) * 512 + e] = (short)rne_bf16(w);
    }
    const int t2 = i - 14 * 2 * 512;
    if (t2 >= 0 && t2 < 27 * 4 * 512) {   // Wp2: [k][cb][512]
        int k = t2 / 2048, r = t2 % 2048, cb = r / 512, e = r % 512;
        int lane = e / 8, j = e % 8, ci = (lane >> 4) * 8 + j, co = cb * 16 + (lane & 15);
        wp2[(k * 4 + cb) * 512 + e] = (short)rne_bf16(W2[(k * NC1 + ci) * NC2 + co]);
    }
    if (i < m4) out2[i] = (float)oc[i];   // out_coors passthrough
    if (i == m4) out2[m4] = (float)bs[0];
}

// wave = 32 output voxels (2 M-tiles). Block = 4 waves = 128 voxels, lockstep
// over the 14 K=32 offset-pairs; per-pair weights (2KB) shared via LDS
// double-buffer (reg-staged one pair ahead). 2-deep idx / 1-deep A pipeline.
__global__ __launch_bounds__(256, 4) void conv1_k(
    const unsigned short* __restrict__ featb, const int* __restrict__ coors,
    const short* __restrict__ wp1,
    const float* __restrict__ g1, const float* __restrict__ b1,
    const float* __restrict__ m1, const float* __restrict__ v1,
    const int* __restrict__ gridp, unsigned short* __restrict__ f1, int n, int tail0) {
    const int tid = threadIdx.x;
    const int lane = tid & 63;
    const int quad = lane >> 4;
    const int mrow = lane & 15;
    const int vbase = blockIdx.x * 128 + (tid >> 6) * 32;
    const int ko_add = quad >> 1;     // this quad's offset within the pair
    const int ci_half = quad & 1;     // this quad's input-channel half

    __shared__ short lw[2][1024];     // [buf][pair-block: 2 cb x 512]

    int pb[2];
#pragma unroll
    for (int mt = 0; mt < 2; ++mt) {
        const int v = vbase + mt * 16 + mrow;
        if (v < n) {
            const int4 cc = ((const int4*)coors)[v];
            pb[mt] = ((cc.x * ZP + cc.y) * YP + cc.z) * XP + cc.w;
        } else {
            pb[mt] = tail0;   // always-(-1) tail region
        }
    }

    floatx4 d[2][2];
#pragma unroll
    for (int mt = 0; mt < 2; ++mt)
#pragma unroll
        for (int cb = 0; cb < 2; ++cb) d[mt][cb] = (floatx4){0.f, 0.f, 0.f, 0.f};

    const short8* __restrict__ wg = (const short8*)wp1;   // 128 short8 per pair-block

    // prologue: stage pair 0 weights into LDS; idx pair0/pair1; A pair0
    if (tid < 128) ((short8*)lw[0])[tid] = wg[tid];
    int id_c[2], id_n[2];
    {
        const int koff = KOFF[ko_add];
#pragma unroll
        for (int mt = 0; mt < 2; ++mt) id_c[mt] = gridp[pb[mt] + koff];
    }
    {
        const int koff = KOFF[2 + ko_add];
#pragma unroll
        for (int mt = 0; mt < 2; ++mt) id_n[mt] = gridp[pb[mt] + koff];
    }
    short8 a_c[2];
#pragma unroll
    for (int mt = 0; mt < 2; ++mt) {
        a_c[mt] = (short8)0;
        if (id_c[mt] >= 0)
            a_c[mt] = *(const short8*)(featb + (unsigned)(id_c[mt] * NCIN + ci_half * 8));
    }
    __syncthreads();

    int buf = 0;
#pragma unroll 1
    for (int pair = 0; pair < 14; ++pair) {
        // 1. issue global weight load for pair+1 (consumed by ds_write at end)
        const int kst = (pair < 13) ? pair + 1 : 13;
        short8 wreg;
        if (tid < 128) wreg = wg[kst * 128 + tid];

        // 2. read this pair's weight fragments from LDS
        short8 wf0 = ((const short8*)lw[buf])[0 * 64 + lane];
        short8 wf1 = ((const short8*)lw[buf])[1 * 64 + lane];

        unsigned long long bm[2];
#pragma unroll
        for (int mt = 0; mt < 2; ++mt) bm[mt] = __ballot(id_c[mt] >= 0);

        // 3. gather A for pair+1
        short8 a_nx[2];
#pragma unroll
        for (int mt = 0; mt < 2; ++mt) {
            a_nx[mt] = (short8)0;
            if (id_n[mt] >= 0)
                a_nx[mt] = *(const short8*)(featb + (unsigned)(id_n[mt] * NCIN + ci_half * 8));
        }
        // 4. prefetch idx for pair+2
        int id_f[2];
        {
            const int kbase = (pair < 12) ? (pair + 2) * 2 : 26;
            const int koff = KOFF[kbase + ko_add];
#pragma unroll
            for (int mt = 0; mt < 2; ++mt) id_f[mt] = gridp[pb[mt] + koff];
        }

        // 5. MFMA on current pair
#pragma unroll
        for (int mt = 0; mt < 2; ++mt) {
            if (bm[mt]) {
                d[mt][0] = __builtin_amdgcn_mfma_f32_16x16x32_bf16(a_c[mt], wf0, d[mt][0], 0, 0, 0);
                d[mt][1] = __builtin_amdgcn_mfma_f32_16x16x32_bf16(a_c[mt], wf1, d[mt][1], 0, 0, 0);
            }
        }

        // 6. stage pair+1 weights into the other LDS buffer, sync
        if (tid < 128) ((short8*)lw[buf ^ 1])[tid] = wreg;
        __syncthreads();

#pragma unroll
        for (int mt = 0; mt < 2; ++mt) {
            a_c[mt] = a_nx[mt]; id_c[mt] = id_n[mt]; id_n[mt] = id_f[mt];
        }
        buf ^= 1;
    }

    // C/D layout: col = lane&15 (channel), row = quad*4 + reg (voxel)
    const int col = lane & 15;
#pragma unroll
    for (int cb = 0; cb < 2; ++cb) {
        const int ch = cb * 16 + col;
        const float sc = g1[ch] * rsqrtf(v1[ch] + BN_EPS);
        const float sb = b1[ch] - m1[ch] * sc;
#pragma unroll
        for (int mt = 0; mt < 2; ++mt) {
#pragma unroll
            for (int r = 0; r < 4; ++r) {
                const int v = vbase + mt * 16 + quad * 4 + r;
                if (v < n) {
                    const float o = fmaxf(fmaf(d[mt][cb][r], sc, sb), 0.f);
                    f1[(unsigned)(v * NC1 + ch)] = rne_bf16(o);
                }
            }
        }
    }
}

// wave = 32 output voxels (2 M-tiles), N=64 (4 col-blocks), K=32 = ci per offset.
// Block = 128 voxels lockstep over 27 taps; per-tap weights (4KB) shared via
// LDS double-buffer. Same pipeline structure as conv1.
__global__ __launch_bounds__(256, 4) void conv2_k(
    const unsigned short* __restrict__ f1,
    const int* __restrict__ ocoors, const short* __restrict__ wp2,
    const float* __restrict__ g2, const float* __restrict__ b2,
    const float* __restrict__ m2, const float* __restrict__ v2,
    const int* __restrict__ gridp, float* __restrict__ out, int m, int tail0) {
    const int tid = threadIdx.x;
    const int lane = tid & 63;
    const int quad = lane >> 4;
    const int mrow = lane & 15;
    const int vbase = blockIdx.x * 128 + (tid >> 6) * 32;

    __shared__ short lw[2][2048];     // [buf][tap-block: 4 cb x 512]

    int pb[2];
#pragma unroll
    for (int mt = 0; mt < 2; ++mt) {
        const int v = vbase + mt * 16 + mrow;
        if (v < m) {
            const int4 cc = ((const int4*)ocoors)[v];
            pb[mt] = ((cc.x * ZP + 2 * cc.y + 1) * YP + 2 * cc.z) * XP + 2 * cc.w;
        } else {
            pb[mt] = tail0;
        }
    }

    floatx4 d[2][4];
#pragma unroll
    for (int mt = 0; mt < 2; ++mt)
#pragma unroll
        for (int cb = 0; cb < 4; ++cb) d[mt][cb] = (floatx4){0.f, 0.f, 0.f, 0.f};

    const short8* __restrict__ wg = (const short8*)wp2;   // 256 short8 per tap-block

    // prologue: stage tap 0 weights; idx for k=0,1; A for k=0
    ((short8*)lw[0])[tid] = wg[tid];
    int id_c[2], id_n[2];
#pragma unroll
    for (int mt = 0; mt < 2; ++mt) id_c[mt] = gridp[pb[mt] + KOFF[0]];
#pragma unroll
    for (int mt = 0; mt < 2; ++mt) id_n[mt] = gridp[pb[mt] + KOFF[1]];
    short8 a_c[2];
#pragma unroll
    for (int mt = 0; mt < 2; ++mt) {
        a_c[mt] = (short8)0;
        if (id_c[mt] >= 0)
            a_c[mt] = *(const short8*)(f1 + (unsigned)(id_c[mt] * NC1 + quad * 8));
    }
    __syncthreads();

    int buf = 0;
#pragma unroll 1
    for (int k = 0; k < 27; ++k) {
        // 1. issue global weight load for tap k+1
        const int kst = (k < 26) ? k + 1 : 26;
        short8 wreg = wg[kst * 256 + tid];

        // 2. read this tap's weight fragments from LDS
        short8 wf[4];
#pragma unroll
        for (int cb = 0; cb < 4; ++cb)
            wf[cb] = ((const short8*)lw[buf])[cb * 64 + lane];

        unsigned long long bm[2];
#pragma unroll
        for (int mt = 0; mt < 2; ++mt) bm[mt] = __ballot(id_c[mt] >= 0);

        // 3. gather A for tap k+1
        short8 a_nx[2];
#pragma unroll
        for (int mt = 0; mt < 2; ++mt) {
            a_nx[mt] = (short8)0;
            if (id_n[mt] >= 0)
                a_nx[mt] = *(const short8*)(f1 + (unsigned)(id_n[mt] * NC1 + quad * 8));
        }
        // 4. prefetch idx for tap k+2
        int id_f[2];
        {
            const int koff = KOFF[(k < 25) ? k + 2 : 26];
#pragma unroll
            for (int mt = 0; mt < 2; ++mt) id_f[mt] = gridp[pb[mt] + koff];
        }

        // 5. MFMA on current tap
#pragma unroll
        for (int mt = 0; mt < 2; ++mt) {
            if (bm[mt]) {
#pragma unroll
                for (int cb = 0; cb < 4; ++cb)
                    d[mt][cb] = __builtin_amdgcn_mfma_f32_16x16x32_bf16(a_c[mt], wf[cb], d[mt][cb], 0, 0, 0);
            }
        }

        // 6. stage tap k+1 weights into the other buffer, sync
        ((short8*)lw[buf ^ 1])[tid] = wreg;
        __syncthreads();

#pragma unroll
        for (int mt = 0; mt < 2; ++mt) {
            a_c[mt] = a_nx[mt]; id_c[mt] = id_n[mt]; id_n[mt] = id_f[mt];
        }
        buf ^= 1;
    }

    const int col = lane & 15;
#pragma unroll
    for (int cb = 0; cb < 4; ++cb) {
        const int ch = cb * 16 + col;
        const float sc = g2[ch] * rsqrtf(v2[ch] + BN_EPS);
        const float sb = b2[ch] - m2[ch] * sc;
#pragma unroll
        for (int mt = 0; mt < 2; ++mt) {
#pragma unroll
            for (int r = 0; r < 4; ++r) {
                const int v = vbase + mt * 16 + quad * 4 + r;
                if (v < m)
                    out[(unsigned)(v * NC2 + ch)] = fmaxf(fmaf(d[mt][cb][r], sc, sb), 0.f);
            }
        }
    }
}

extern "C" void kernel_launch(void* const* d_in, const int* in_sizes, int n_in,
                              void* d_out, int out_size, void* d_ws, size_t ws_size,
                              hipStream_t stream) {
    const float* feat  = (const float*)d_in[0];
    const int*   coors = (const int*)d_in[1];
    const int*   ocoors= (const int*)d_in[2];
    const float* W1 = (const float*)d_in[3];
    const float* g1 = (const float*)d_in[4];
    const float* b1 = (const float*)d_in[5];
    const float* m1 = (const float*)d_in[6];
    const float* v1 = (const float*)d_in[7];
    const float* W2 = (const float*)d_in[8];
    const float* g2 = (const float*)d_in[9];
    const float* b2 = (const float*)d_in[10];
    const float* m2 = (const float*)d_in[11];
    const float* v2 = (const float*)d_in[12];
    const int*   bs = (const int*)d_in[13];

    const int n = in_sizes[0] / NCIN;
    const int m = in_sizes[2] / 4;

    char* ws = (char*)d_ws;
    int* grid = (int*)ws;
    size_t off = ((size_t)(GRID_TOT + TAILN) * sizeof(int) + 255) & ~(size_t)255;
    unsigned short* featb = (unsigned short*)(ws + off);
    off += ((size_t)n * NCIN * 2 + 255) & ~(size_t)255;
    unsigned short* f1 = (unsigned short*)(ws + off);
    off += ((size_t)n * NC1 * 2 + 255) & ~(size_t)255;
    short* wp1 = (short*)(ws + off);
    off += (14 * 2 * 512 * 2 + 255) & ~(size_t)255;
    short* wp2 = (short*)(ws + off);

    float* out = (float*)d_out;
    float* out2 = out + (size_t)m * NC2;

    // prep must cover the LARGEST of its fused ranges: 2n (feat) vs m*4+1 (coords)
    int prep_threads = 2 * n;
    if (m * 4 + 1 > prep_threads) prep_threads = m * 4 + 1;

    hipMemsetAsync(grid, 0xFF, (size_t)(GRID_TOT + TAILN) * sizeof(int), stream);
    prep_k<<<(prep_threads + 255) / 256, 256, 0, stream>>>(feat, coors, W1, W2, ocoors, bs,
                                                           grid, featb, wp1, wp2, out2, n, m * 4);

    conv1_k<<<(n + 127) / 128, 256, 0, stream>>>(featb, coors, wp1, g1, b1, m1, v1,
                                                 grid, f1, n, GRID_TOT);

    conv2_k<<<(m + 127) / 128, 256, 0, stream>>>(f1, ocoors, wp2,
                                                 g2, b2, m2, v2, grid, out, m, GRID_TOT);
}

// Round 7
// 236.071 us; speedup vs baseline: 1.3434x; 1.0059x over previous
//
#include <hip/hip_runtime.h>

#define ZD 21
#define YD 256
#define XD 256
#define BD 2
#define NCIN 16
#define NC1 32
#define NC2 64
#define BN_EPS 1e-3f

// halo-padded rulebook grid: z,y,x each padded by 1 on both sides
#define ZP 23
#define YP 258
#define XP 258
#define YPXP 66564               // YP*XP
#define GRID_TOT (BD * ZP * YPXP)  // 3,061,944
#define TAILN 133647             // max KOFF + 1; always-zero region for invalid rows

typedef __attribute__((ext_vector_type(8))) short short8;
typedef __attribute__((ext_vector_type(4))) float floatx4;

// KOFF[k] = dz*YPXP + dy*XP + dx for (dz,dy,dx) in {0,1,2}^3 lexicographic; [27] = 0 pad
__constant__ int KOFF[28] = {
    0, 1, 2, 258, 259, 260, 516, 517, 518,
    66564, 66565, 66566, 66822, 66823, 66824, 67080, 67081, 67082,
    133128, 133129, 133130, 133386, 133387, 133388, 133644, 133645, 133646,
    0};

__device__ inline unsigned short rne_bf16(float w) {
    unsigned b = __float_as_uint(w);
    return (unsigned short)((b + 0x7FFFu + ((b >> 16) & 1u)) >> 16);
}

// Fused prep: grid scatter (+1 encoding) + feat->bf16 (rows shifted by 1, row 0
// zeroed) + f1 zero row + weight packing + out_coors tail.
// Grid must cover max(2n, m4+1) threads.
__global__ __launch_bounds__(256) void prep_k(
    const float* __restrict__ feat, const int* __restrict__ coors,
    const float* __restrict__ W1, const float* __restrict__ W2,
    const int* __restrict__ oc, const int* __restrict__ bs,
    int* __restrict__ grid, unsigned short* __restrict__ featb,
    unsigned short* __restrict__ f1,
    short* __restrict__ wp1, short* __restrict__ wp2,
    float* __restrict__ out2, int n, int m4) {
    const int i = blockIdx.x * 256 + threadIdx.x;

    if (i < n) {                          // scatter voxel id+1 (0 = empty/zero-row)
        const int4 c = ((const int4*)coors)[i];   // [b, z, y, x]
        grid[((c.x * ZP + c.y + 1) * YP + c.z + 1) * XP + c.w + 1] = i + 1;
    }
    if (i < 2 * n) {                      // feat f32 -> bf16; voxel i -> row i+1
        const float4* p = (const float4*)feat + (size_t)i * 2;
        const float4 a = p[0], b = p[1];
        short8 o;
        o[0] = (short)rne_bf16(a.x); o[1] = (short)rne_bf16(a.y);
        o[2] = (short)rne_bf16(a.z); o[3] = (short)rne_bf16(a.w);
        o[4] = (short)rne_bf16(b.x); o[5] = (short)rne_bf16(b.y);
        o[6] = (short)rne_bf16(b.z); o[7] = (short)rne_bf16(b.w);
        ((short8*)featb)[i + 2] = o;      // slot (voxel+1)*2 + half
    }
    if (i < 2) ((short8*)featb)[i] = (short8)0;   // zero row 0 of featb
    if (i < 4) ((short8*)f1)[i] = (short8)0;      // zero row 0 of f1
    if (i < 14 * 2 * 512) {               // Wp1: [pair][cb][512]
        int pair = i / 1024, r = i % 1024, cb = r / 512, e = r % 512;
        int lane = e / 8, j = e % 8, kk = (lane >> 4) * 8 + j;
        int ko = pair * 2 + (kk >> 4), ci = kk & 15, co = cb * 16 + (lane & 15);
        float w = (ko < 27) ? W1[(ko * NCIN + ci) * NC1 + co] : 0.f;
        wp1[(pair * 2 + cb) * 512 + e] = (short)rne_bf16(w);
    }
    const int t2 = i - 14 * 2 * 512;
    if (t2 >= 0 && t2 < 27 * 4 * 512) {   // Wp2: [k][cb][512]
        int k = t2 / 2048, r = t2 % 2048, cb = r / 512, e = r % 512;
        int lane = e / 8, j = e % 8, ci = (lane >> 4) * 8 + j, co = cb * 16 + (lane & 15);
        wp2[(k * 4 + cb) * 512 + e] = (short)rne_bf16(W2[(k * NC1 + ci) * NC2 + co]);
    }
    if (i < m4) out2[i] = (float)oc[i];   // out_coors passthrough
    if (i == m4) out2[m4] = (float)bs[0];
}

// wave = 32 output voxels (2 M-tiles). Block = 4 waves = 128 voxels, lockstep
// over the 14 K=32 offset-pairs; per-pair weights (2KB) shared via LDS
// double-buffer. BRANCHLESS K-loop: grid yields row 0 (all-zero) for empty
// neighbors, so gathers and MFMAs run unconditionally.
__global__ __launch_bounds__(256, 4) void conv1_k(
    const unsigned short* __restrict__ featb, const int* __restrict__ coors,
    const short* __restrict__ wp1,
    const float* __restrict__ g1, const float* __restrict__ b1,
    const float* __restrict__ m1, const float* __restrict__ v1,
    const int* __restrict__ gridp, unsigned short* __restrict__ f1, int n, int tail0) {
    const int tid = threadIdx.x;
    const int lane = tid & 63;
    const int quad = lane >> 4;
    const int mrow = lane & 15;
    const int vbase = blockIdx.x * 128 + (tid >> 6) * 32;
    const int ko_add = quad >> 1;     // this quad's offset within the pair
    const int ci_half = quad & 1;     // this quad's input-channel half

    __shared__ short lw[2][1024];     // [buf][pair-block: 2 cb x 512]

    int pb[2];
#pragma unroll
    for (int mt = 0; mt < 2; ++mt) {
        const int v = vbase + mt * 16 + mrow;
        if (v < n) {
            const int4 cc = ((const int4*)coors)[v];
            pb[mt] = ((cc.x * ZP + cc.y) * YP + cc.z) * XP + cc.w;
        } else {
            pb[mt] = tail0;   // always-zero tail region
        }
    }

    floatx4 d[2][2];
#pragma unroll
    for (int mt = 0; mt < 2; ++mt)
#pragma unroll
        for (int cb = 0; cb < 2; ++cb) d[mt][cb] = (floatx4){0.f, 0.f, 0.f, 0.f};

    const short8* __restrict__ wg = (const short8*)wp1;   // 128 short8 per pair-block

    // prologue: stage pair 0 weights into LDS; idx pair0/pair1; A pair0
    if (tid < 128) ((short8*)lw[0])[tid] = wg[tid];
    int id_c[2], id_n[2];
    {
        const int koff = KOFF[ko_add];
#pragma unroll
        for (int mt = 0; mt < 2; ++mt) id_c[mt] = gridp[pb[mt] + koff];
    }
    {
        const int koff = KOFF[2 + ko_add];
#pragma unroll
        for (int mt = 0; mt < 2; ++mt) id_n[mt] = gridp[pb[mt] + koff];
    }
    short8 a_c[2];
#pragma unroll
    for (int mt = 0; mt < 2; ++mt)
        a_c[mt] = *(const short8*)(featb + (unsigned)(id_c[mt] * NCIN + ci_half * 8));
    __syncthreads();

    int buf = 0;
#pragma unroll 1
    for (int pair = 0; pair < 14; ++pair) {
        // 1. issue global weight load for pair+1
        const int kst = (pair < 13) ? pair + 1 : 13;
        short8 wreg;
        if (tid < 128) wreg = wg[kst * 128 + tid];

        // 2. read this pair's weight fragments from LDS
        short8 wf0 = ((const short8*)lw[buf])[0 * 64 + lane];
        short8 wf1 = ((const short8*)lw[buf])[1 * 64 + lane];

        // 3. gather A for pair+1 (unconditional; row 0 = zeros)
        short8 a_nx[2];
#pragma unroll
        for (int mt = 0; mt < 2; ++mt)
            a_nx[mt] = *(const short8*)(featb + (unsigned)(id_n[mt] * NCIN + ci_half * 8));

        // 4. prefetch idx for pair+2
        int id_f[2];
        {
            const int kbase = (pair < 12) ? (pair + 2) * 2 : 26;
            const int koff = KOFF[kbase + ko_add];
#pragma unroll
            for (int mt = 0; mt < 2; ++mt) id_f[mt] = gridp[pb[mt] + koff];
        }

        // 5. MFMA on current pair (unconditional)
#pragma unroll
        for (int mt = 0; mt < 2; ++mt) {
            d[mt][0] = __builtin_amdgcn_mfma_f32_16x16x32_bf16(a_c[mt], wf0, d[mt][0], 0, 0, 0);
            d[mt][1] = __builtin_amdgcn_mfma_f32_16x16x32_bf16(a_c[mt], wf1, d[mt][1], 0, 0, 0);
        }

        // 6. stage pair+1 weights into the other LDS buffer, sync
        if (tid < 128) ((short8*)lw[buf ^ 1])[tid] = wreg;
        __syncthreads();

#pragma unroll
        for (int mt = 0; mt < 2; ++mt) {
            a_c[mt] = a_nx[mt]; id_c[mt] = id_n[mt]; id_n[mt] = id_f[mt];
        }
        buf ^= 1;
    }

    // C/D layout: col = lane&15 (channel), row = quad*4 + reg (voxel)
    const int col = lane & 15;
#pragma unroll
    for (int cb = 0; cb < 2; ++cb) {
        const int ch = cb * 16 + col;
        const float sc = g1[ch] * rsqrtf(v1[ch] + BN_EPS);
        const float sb = b1[ch] - m1[ch] * sc;
#pragma unroll
        for (int mt = 0; mt < 2; ++mt) {
#pragma unroll
            for (int r = 0; r < 4; ++r) {
                const int v = vbase + mt * 16 + quad * 4 + r;
                if (v < n) {
                    const float o = fmaxf(fmaf(d[mt][cb][r], sc, sb), 0.f);
                    f1[(unsigned)((v + 1) * NC1 + ch)] = rne_bf16(o);   // row v+1
                }
            }
        }
    }
}

// wave = 32 output voxels (2 M-tiles), N=64 (4 col-blocks), K=32 = ci per offset.
// Block = 128 voxels lockstep over 27 taps; per-tap weights (4KB) via LDS
// double-buffer. BRANCHLESS: row 0 of f1 is the zero row.
__global__ __launch_bounds__(256, 4) void conv2_k(
    const unsigned short* __restrict__ f1,
    const int* __restrict__ ocoors, const short* __restrict__ wp2,
    const float* __restrict__ g2, const float* __restrict__ b2,
    const float* __restrict__ m2, const float* __restrict__ v2,
    const int* __restrict__ gridp, float* __restrict__ out, int m, int tail0) {
    const int tid = threadIdx.x;
    const int lane = tid & 63;
    const int quad = lane >> 4;
    const int mrow = lane & 15;
    const int vbase = blockIdx.x * 128 + (tid >> 6) * 32;

    __shared__ short lw[2][2048];     // [buf][tap-block: 4 cb x 512]

    int pb[2];
#pragma unroll
    for (int mt = 0; mt < 2; ++mt) {
        const int v = vbase + mt * 16 + mrow;
        if (v < m) {
            const int4 cc = ((const int4*)ocoors)[v];
            pb[mt] = ((cc.x * ZP + 2 * cc.y + 1) * YP + 2 * cc.z) * XP + 2 * cc.w;
        } else {
            pb[mt] = tail0;
        }
    }

    floatx4 d[2][4];
#pragma unroll
    for (int mt = 0; mt < 2; ++mt)
#pragma unroll
        for (int cb = 0; cb < 4; ++cb) d[mt][cb] = (floatx4){0.f, 0.f, 0.f, 0.f};

    const short8* __restrict__ wg = (const short8*)wp2;   // 256 short8 per tap-block

    // prologue: stage tap 0 weights; idx for k=0,1; A for k=0
    ((short8*)lw[0])[tid] = wg[tid];
    int id_c[2], id_n[2];
#pragma unroll
    for (int mt = 0; mt < 2; ++mt) id_c[mt] = gridp[pb[mt] + KOFF[0]];
#pragma unroll
    for (int mt = 0; mt < 2; ++mt) id_n[mt] = gridp[pb[mt] + KOFF[1]];
    short8 a_c[2];
#pragma unroll
    for (int mt = 0; mt < 2; ++mt)
        a_c[mt] = *(const short8*)(f1 + (unsigned)(id_c[mt] * NC1 + quad * 8));
    __syncthreads();

    int buf = 0;
#pragma unroll 1
    for (int k = 0; k < 27; ++k) {
        // 1. issue global weight load for tap k+1
        const int kst = (k < 26) ? k + 1 : 26;
        short8 wreg = wg[kst * 256 + tid];

        // 2. read this tap's weight fragments from LDS
        short8 wf[4];
#pragma unroll
        for (int cb = 0; cb < 4; ++cb)
            wf[cb] = ((const short8*)lw[buf])[cb * 64 + lane];

        // 3. gather A for tap k+1 (unconditional; row 0 = zeros)
        short8 a_nx[2];
#pragma unroll
        for (int mt = 0; mt < 2; ++mt)
            a_nx[mt] = *(const short8*)(f1 + (unsigned)(id_n[mt] * NC1 + quad * 8));

        // 4. prefetch idx for tap k+2
        int id_f[2];
        {
            const int koff = KOFF[(k < 25) ? k + 2 : 26];
#pragma unroll
            for (int mt = 0; mt < 2; ++mt) id_f[mt] = gridp[pb[mt] + koff];
        }

        // 5. MFMA on current tap (unconditional)
#pragma unroll
        for (int mt = 0; mt < 2; ++mt) {
#pragma unroll
            for (int cb = 0; cb < 4; ++cb)
                d[mt][cb] = __builtin_amdgcn_mfma_f32_16x16x32_bf16(a_c[mt], wf[cb], d[mt][cb], 0, 0, 0);
        }

        // 6. stage tap k+1 weights into the other buffer, sync
        ((short8*)lw[buf ^ 1])[tid] = wreg;
        __syncthreads();

#pragma unroll
        for (int mt = 0; mt < 2; ++mt) {
            a_c[mt] = a_nx[mt]; id_c[mt] = id_n[mt]; id_n[mt] = id_f[mt];
        }
        buf ^= 1;
    }

    const int col = lane & 15;
#pragma unroll
    for (int cb = 0; cb < 4; ++cb) {
        const int ch = cb * 16 + col;
        const float sc = g2[ch] * rsqrtf(v2[ch] + BN_EPS);
        const float sb = b2[ch] - m2[ch] * sc;
#pragma unroll
        for (int mt = 0; mt < 2; ++mt) {
#pragma unroll
            for (int r = 0; r < 4; ++r) {
                const int v = vbase + mt * 16 + quad * 4 + r;
                if (v < m)
                    out[(unsigned)(v * NC2 + ch)] = fmaxf(fmaf(d[mt][cb][r], sc, sb), 0.f);
            }
        }
    }
}

extern "C" void kernel_launch(void* const* d_in, const int* in_sizes, int n_in,
                              void* d_out, int out_size, void* d_ws, size_t ws_size,
                              hipStream_t stream) {
    const float* feat  = (const float*)d_in[0];
    const int*   coors = (const int*)d_in[1];
    const int*   ocoors= (const int*)d_in[2];
    const float* W1 = (const float*)d_in[3];
    const float* g1 = (const float*)d_in[4];
    const float* b1 = (const float*)d_in[5];
    const float* m1 = (const float*)d_in[6];
    const float* v1 = (const float*)d_in[7];
    const float* W2 = (const float*)d_in[8];
    const float* g2 = (const float*)d_in[9];
    const float* b2 = (const float*)d_in[10];
    const float* m2 = (const float*)d_in[11];
    const float* v2 = (const float*)d_in[12];
    const int*   bs = (const int*)d_in[13];

    const int n = in_sizes[0] / NCIN;
    const int m = in_sizes[2] / 4;

    char* ws = (char*)d_ws;
    int* grid = (int*)ws;
    size_t off = ((size_t)(GRID_TOT + TAILN) * sizeof(int) + 255) & ~(size_t)255;
    unsigned short* featb = (unsigned short*)(ws + off);
    off += ((size_t)(n + 1) * NCIN * 2 + 255) & ~(size_t)255;   // +1 zero row
    unsigned short* f1 = (unsigned short*)(ws + off);
    off += ((size_t)(n + 1) * NC1 * 2 + 255) & ~(size_t)255;    // +1 zero row
    short* wp1 = (short*)(ws + off);
    off += (14 * 2 * 512 * 2 + 255) & ~(size_t)255;
    short* wp2 = (short*)(ws + off);

    float* out = (float*)d_out;
    float* out2 = out + (size_t)m * NC2;

    // prep must cover the LARGEST of its fused ranges: 2n (feat) vs m*4+1 (coords)
    int prep_threads = 2 * n;
    if (m * 4 + 1 > prep_threads) prep_threads = m * 4 + 1;

    hipMemsetAsync(grid, 0x00, (size_t)(GRID_TOT + TAILN) * sizeof(int), stream);
    prep_k<<<(prep_threads + 255) / 256, 256, 0, stream>>>(feat, coors, W1, W2, ocoors, bs,
                                                           grid, featb, f1, wp1, wp2, out2, n, m * 4);

    conv1_k<<<(n + 127) / 128, 256, 0, stream>>>(featb, coors, wp1, g1, b1, m1, v1,
                                                 grid, f1, n, GRID_TOT);

    conv2_k<<<(m + 127) / 128, 256, 0, stream>>>(f1, ocoors, wp2,
                                                 g2, b2, m2, v2, grid, out, m, GRID_TOT);
}